// Round 2
// baseline (11882.001 us; speedup 1.0000x reference)
//
#include <hip/hip_runtime.h>
#include <hip/hip_bf16.h>

#define NN 100000
#define NE 1600000
#define XD 4
#define ED 39
#define K1 43   // XD+ED
#define H1 64
#define H2 128
#define H3 256
#define NB 32   // nodes per block in node kernel

// ---------------- edge kernel: h2 = relu(relu([x[col]||ea] W1 + b1) W2 + b2); atomic scatter by row
__global__ __launch_bounds__(256) void edge_kernel(
    const float* __restrict__ x, const int* __restrict__ eidx,
    const float* __restrict__ ea,
    const float* __restrict__ W1, const float* __restrict__ b1,
    const float* __restrict__ W2, const float* __restrict__ b2,
    float* __restrict__ s, float* __restrict__ cnt)
{
    __shared__ float sW1[K1 * H1];        // 11008 B
    __shared__ float sW2[H1 * H2];        // 32768 B
    __shared__ float sB1[H1];
    __shared__ float sB2[H2];
    __shared__ float sIn[64 * K1];        // stride 43 (odd -> conflict-free)
    __shared__ float sH[64 * (H1 + 1)];   // stride 65 (odd -> conflict-free)

    const int t  = threadIdx.x;
    const int e0 = blockIdx.x * 64;

    for (int i = t; i < K1 * H1; i += 256) sW1[i] = W1[i];
    for (int i = t; i < H1 * H2; i += 256) sW2[i] = W2[i];
    if (t < H1) sB1[t] = b1[t];
    if (t < H2) sB2[t] = b2[t];

    // stage gathered x (4 dims per edge): 4 threads per edge
    {
        int e = t >> 2, k = t & 3;
        int src = eidx[NE + e0 + e];      // second row = col (source nodes)
        sIn[e * K1 + k] = x[src * XD + k];
    }
    // stage edge_attr (contiguous, coalesced)
    for (int i = t; i < 64 * ED; i += 256) {
        int e = i / ED, k = i - e * ED;
        sIn[e * K1 + XD + k] = ea[(size_t)(e0 + e) * ED + k];
    }
    __syncthreads();

    const int lane = t & 63;   // edge within tile
    const int g    = t >> 6;   // wave id: output-slice group

    // layer 1: wave g -> outputs [g*16, g*16+16)
    {
        const int jb = g * 16;
        float acc[16];
        #pragma unroll
        for (int i = 0; i < 16; i++) acc[i] = sB1[jb + i];
        for (int k = 0; k < K1; k++) {
            float a = sIn[lane * K1 + k];
            #pragma unroll
            for (int i = 0; i < 16; i++)
                acc[i] = fmaf(a, sW1[k * H1 + jb + i], acc[i]);
        }
        #pragma unroll
        for (int i = 0; i < 16; i++)
            sH[lane * (H1 + 1) + jb + i] = fmaxf(acc[i], 0.f);
    }
    __syncthreads();

    // layer 2: wave g -> outputs [g*32, g*32+32), then atomic scatter
    {
        const int jb = g * 32;
        float acc[32];
        #pragma unroll
        for (int i = 0; i < 32; i++) acc[i] = sB2[jb + i];
        for (int k = 0; k < H1; k++) {
            float a = sH[lane * (H1 + 1) + k];
            #pragma unroll
            for (int i = 0; i < 32; i++)
                acc[i] = fmaf(a, sW2[k * H2 + jb + i], acc[i]);
        }
        const int dst = eidx[e0 + lane];  // first row = row (dest nodes)
        float* srow = s + (size_t)dst * H2 + jb;
        #pragma unroll
        for (int i = 0; i < 32; i++)
            atomicAdd(&srow[i], fmaxf(acc[i], 0.f));
        if (g == 0) atomicAdd(&cnt[dst], 1.0f);
    }
}

// ---------------- node kernel: o = relu(relu([x||mean] W3 + b3) W4 + b4)
__global__ __launch_bounds__(256) void node_kernel(
    const float* __restrict__ x,
    const float* __restrict__ W3, const float* __restrict__ b3,
    const float* __restrict__ W4, const float* __restrict__ b4,
    const float* __restrict__ s, const float* __restrict__ cnt,
    float* __restrict__ out)
{
    __shared__ float sIn[NB * 132];   // k-reads are wave-broadcast -> conflict-free
    __shared__ float sO1[NB * H3];
    __shared__ float sInv[NB];

    const int t  = threadIdx.x;
    const int n0 = blockIdx.x * NB;

    if (t < NB) {
        float c = cnt[n0 + t];
        sInv[t] = 1.0f / fmaxf(c, 1.0f);
    }
    __syncthreads();

    for (int i = t; i < NB * 132; i += 256) {
        int n = i / 132, k = i - n * 132;
        float v;
        if (k < XD) v = x[(n0 + n) * XD + k];
        else        v = s[(size_t)(n0 + n) * H2 + (k - XD)] * sInv[n];
        sIn[i] = v;
    }
    __syncthreads();

    // layer 3: thread t owns output column t, NB node accumulators
    {
        float acc[NB];
        float bj = b3[t];
        #pragma unroll
        for (int n = 0; n < NB; n++) acc[n] = bj;
        for (int k = 0; k < 132; k++) {
            float w = W3[k * H3 + t];   // coalesced across lanes, L2-hot
            #pragma unroll
            for (int n = 0; n < NB; n++)
                acc[n] = fmaf(sIn[n * 132 + k], w, acc[n]);
        }
        #pragma unroll
        for (int n = 0; n < NB; n++)
            sO1[n * H3 + t] = fmaxf(acc[n], 0.f);
    }
    __syncthreads();

    // layer 4
    {
        float acc[NB];
        float bj = b4[t];
        #pragma unroll
        for (int n = 0; n < NB; n++) acc[n] = bj;
        for (int k = 0; k < H3; k++) {
            float w = W4[k * H3 + t];
            #pragma unroll
            for (int n = 0; n < NB; n++)
                acc[n] = fmaf(sO1[n * H3 + k], w, acc[n]);
        }
        #pragma unroll
        for (int n = 0; n < NB; n++)
            out[(size_t)(n0 + n) * H3 + t] = fmaxf(acc[n], 0.f);
    }
}

extern "C" void kernel_launch(void* const* d_in, const int* in_sizes, int n_in,
                              void* d_out, int out_size, void* d_ws, size_t ws_size,
                              hipStream_t stream) {
    const float* x    = (const float*)d_in[0];
    const int*   eidx = (const int*)  d_in[1];
    const float* ea   = (const float*)d_in[2];
    const float* W1   = (const float*)d_in[3];
    const float* b1   = (const float*)d_in[4];
    const float* W2   = (const float*)d_in[5];
    const float* b2   = (const float*)d_in[6];
    const float* W3   = (const float*)d_in[7];
    const float* b3   = (const float*)d_in[8];
    const float* W4   = (const float*)d_in[9];
    const float* b4   = (const float*)d_in[10];
    float* out = (float*)d_out;

    float* s   = (float*)d_ws;                 // [NN,128] f32 accumulator
    float* cnt = s + (size_t)NN * H2;          // [NN] f32 counts

    hipMemsetAsync(d_ws, 0, ((size_t)NN * H2 + NN) * sizeof(float), stream);

    edge_kernel<<<NE / 64, 256, 0, stream>>>(x, eidx, ea, W1, b1, W2, b2, s, cnt);
    node_kernel<<<NN / NB, 256, 0, stream>>>(x, W3, b3, W4, b4, s, cnt, out);
}

// Round 3
// 2573.320 us; speedup vs baseline: 4.6174x; 4.6174x over previous
//
#include <hip/hip_runtime.h>
#include <hip/hip_bf16.h>

#define NN 100000
#define NE 1600000
#define XD 4
#define ED 39
#define K1 43   // XD+ED
#define H1 64
#define H2 128
#define H3 256
#define NB 32   // nodes per block in node kernel
#define NBN 8   // nodes per block in edge_agg kernel

// ---------------- pass 1: indegree histogram
__global__ __launch_bounds__(256) void hist_kernel(const int* __restrict__ eidx,
                                                   int* __restrict__ cnt) {
    int e = blockIdx.x * 256 + threadIdx.x;
    if (e < NE) atomicAdd(&cnt[eidx[e]], 1);
}

// ---------------- pass 2: single-block scan -> row_ptr (incl-shifted) + cursor (excl)
__global__ __launch_bounds__(1024) void scan_kernel(const int* __restrict__ cnt,
                                                    int* __restrict__ row_ptr,
                                                    int* __restrict__ cursor) {
    __shared__ int wsum[16];
    const int t = threadIdx.x, lane = t & 63, w = t >> 6;
    int carry = 0;
    if (t == 0) row_ptr[0] = 0;
    for (int base = 0; base < NN; base += 1024) {
        int i = base + t;
        int v = (i < NN) ? cnt[i] : 0;
        int s = v;
        #pragma unroll
        for (int d = 1; d < 64; d <<= 1) {
            int u = __shfl_up(s, d, 64);
            if (lane >= d) s += u;
        }
        if (lane == 63) wsum[w] = s;
        __syncthreads();
        if (w == 0 && lane < 16) {
            int e = wsum[lane];
            #pragma unroll
            for (int d = 1; d < 16; d <<= 1) {
                int u = __shfl_up(e, d, 64);
                if (lane >= d) e += u;
            }
            wsum[lane] = e;
        }
        __syncthreads();
        int woff = (w == 0) ? 0 : wsum[w - 1];
        int tot  = wsum[15];
        if (i < NN) {
            int incl = carry + woff + s;
            row_ptr[i + 1] = incl;
            cursor[i]      = incl - v;
        }
        carry += tot;
        __syncthreads();   // protect wsum before next tile overwrites
    }
}

// ---------------- pass 3: scatter edge ids into dst-sorted order
__global__ __launch_bounds__(256) void build_kernel(const int* __restrict__ eidx,
                                                    int* __restrict__ cursor,
                                                    int* __restrict__ perm) {
    int e = blockIdx.x * 256 + threadIdx.x;
    if (e < NE) {
        int r = eidx[e];
        int pos = atomicAdd(&cursor[r], 1);
        perm[pos] = e;
    }
}

// ---------------- pass 4: edge MLP + deterministic per-node aggregation
__global__ __launch_bounds__(256) void edge_agg_kernel(
    const float* __restrict__ x, const int* __restrict__ eidx,
    const float* __restrict__ ea,
    const float* __restrict__ W1, const float* __restrict__ b1,
    const float* __restrict__ W2, const float* __restrict__ b2,
    const int* __restrict__ row_ptr, const int* __restrict__ perm,
    float* __restrict__ mean)
{
    __shared__ float sW1[K1 * H1];          // 11008 B
    __shared__ float sW2[H1 * H2];          // 32768 B
    __shared__ float sB1[H1];
    __shared__ float sB2[H2];
    __shared__ float u[64 * K1 + 64 * (H1 + 1)];  // 6912 floats, 27648 B (sIn | sH, reused as sH2)
    __shared__ float accs[NBN][H2];         // 4096 B
    __shared__ int   sPerm[64];
    __shared__ int   sCol[64];
    __shared__ int   sRP[NBN + 1];

    const int t  = threadIdx.x;
    const int n0 = blockIdx.x * NBN;
    const int lane = t & 63;
    const int g    = t >> 6;

    for (int i = t; i < K1 * H1; i += 256) sW1[i] = W1[i];
    for (int i = t; i < H1 * H2; i += 256) sW2[i] = W2[i];
    if (t < H1) sB1[t] = b1[t];
    if (t < H2) sB2[t] = b2[t];
    if (t <= NBN) sRP[t] = row_ptr[n0 + t];
    for (int i = t; i < NBN * H2; i += 256) ((float*)accs)[i] = 0.f;
    __syncthreads();

    const int base = sRP[0], end = sRP[NBN];
    const int cntE = end - base;
    float* sIn = u;                 // [64][43]
    float* sH  = u + 64 * K1;       // [64][65]

    for (int tb = 0; tb < cntE; tb += 64) {
        const int nv = min(64, cntE - tb);
        if (t < 64) {
            int e = (t < nv) ? perm[base + tb + t] : -1;
            sPerm[t] = e;
            sCol[t]  = (e >= 0) ? eidx[NE + e] : 0;   // second row = col (source)
        }
        __syncthreads();
        for (int i = t; i < 64 * K1; i += 256) {
            int j = i / K1, k = i - j * K1;
            int e = sPerm[j];
            float v = 0.f;
            if (e >= 0) v = (k < XD) ? x[sCol[j] * XD + k]
                                     : ea[(size_t)e * ED + (k - XD)];
            sIn[j * K1 + k] = v;
        }
        __syncthreads();

        // layer 1: wave g -> cols [g*16, g*16+16)
        {
            const int jb = g * 16;
            float acc[16];
            #pragma unroll
            for (int i = 0; i < 16; i++) acc[i] = sB1[jb + i];
            for (int k = 0; k < K1; k++) {
                float a = sIn[lane * K1 + k];
                #pragma unroll
                for (int i = 0; i < 16; i++)
                    acc[i] = fmaf(a, sW1[k * H1 + jb + i], acc[i]);
            }
            #pragma unroll
            for (int i = 0; i < 16; i++)
                sH[lane * (H1 + 1) + jb + i] = fmaxf(acc[i], 0.f);
        }
        __syncthreads();

        // layer 2: wave g -> cols [g*32, g*32+32)
        float acc2[32];
        {
            const int jb = g * 32;
            #pragma unroll
            for (int i = 0; i < 32; i++) acc2[i] = sB2[jb + i];
            for (int k = 0; k < H1; k++) {
                float a = sH[lane * (H1 + 1) + k];
                #pragma unroll
                for (int i = 0; i < 32; i++)
                    acc2[i] = fmaf(a, sW2[k * H2 + jb + i], acc2[i]);
            }
        }
        __syncthreads();   // u (sIn/sH) now dead, safe to overwrite

        // segment-reduce h2 per node, two 64-col passes through u as sH2[64][65]
        #pragma unroll
        for (int half = 0; half < 2; half++) {
            if ((g >> 1) == half) {
                const int cb = (g & 1) * 32;
                #pragma unroll
                for (int i = 0; i < 32; i++)
                    u[lane * (H1 + 1) + cb + i] = fmaxf(acc2[i], 0.f);
            }
            __syncthreads();
            if (t < 128) {
                const int c = t & 63, grp = t >> 6;
                for (int n = grp * 4; n < grp * 4 + 4; n++) {
                    int lo = sRP[n] - base - tb;     lo = lo < 0 ? 0 : lo;
                    int hi = sRP[n + 1] - base - tb; hi = hi > nv ? nv : hi;
                    float sum = 0.f;
                    for (int j = lo; j < hi; j++) sum += u[j * (H1 + 1) + c];
                    accs[n][half * 64 + c] += sum;
                }
            }
            __syncthreads();
        }
    }

    // write mean (exclusive ownership, non-atomic)
    for (int i = t; i < NBN * H2; i += 256) {
        int n = i >> 7, c = i & 127;
        int deg = sRP[n + 1] - sRP[n];
        float inv = (deg > 0) ? 1.f / (float)deg : 0.f;
        mean[(size_t)(n0 + n) * H2 + c] = accs[n][c] * inv;
    }
}

// ---------------- pass 5: node MLP: o = relu(relu([x||mean] W3 + b3) W4 + b4)
__global__ __launch_bounds__(256) void node_kernel(
    const float* __restrict__ x,
    const float* __restrict__ W3, const float* __restrict__ b3,
    const float* __restrict__ W4, const float* __restrict__ b4,
    const float* __restrict__ mean,
    float* __restrict__ out)
{
    __shared__ float sIn[NB * 132];
    __shared__ float sO1[NB * H3];

    const int t  = threadIdx.x;
    const int n0 = blockIdx.x * NB;

    for (int i = t; i < NB * 132; i += 256) {
        int n = i / 132, k = i - n * 132;
        float v;
        if (k < XD) v = x[(n0 + n) * XD + k];
        else        v = mean[(size_t)(n0 + n) * H2 + (k - XD)];
        sIn[i] = v;
    }
    __syncthreads();

    {
        float acc[NB];
        float bj = b3[t];
        #pragma unroll
        for (int n = 0; n < NB; n++) acc[n] = bj;
        for (int k = 0; k < 132; k++) {
            float w = W3[k * H3 + t];
            #pragma unroll
            for (int n = 0; n < NB; n++)
                acc[n] = fmaf(sIn[n * 132 + k], w, acc[n]);
        }
        #pragma unroll
        for (int n = 0; n < NB; n++)
            sO1[n * H3 + t] = fmaxf(acc[n], 0.f);
    }
    __syncthreads();

    {
        float acc[NB];
        float bj = b4[t];
        #pragma unroll
        for (int n = 0; n < NB; n++) acc[n] = bj;
        for (int k = 0; k < H3; k++) {
            float w = W4[k * H3 + t];
            #pragma unroll
            for (int n = 0; n < NB; n++)
                acc[n] = fmaf(sO1[n * H3 + k], w, acc[n]);
        }
        #pragma unroll
        for (int n = 0; n < NB; n++)
            out[(size_t)(n0 + n) * H3 + t] = fmaxf(acc[n], 0.f);
    }
}

extern "C" void kernel_launch(void* const* d_in, const int* in_sizes, int n_in,
                              void* d_out, int out_size, void* d_ws, size_t ws_size,
                              hipStream_t stream) {
    const float* x    = (const float*)d_in[0];
    const int*   eidx = (const int*)  d_in[1];
    const float* ea   = (const float*)d_in[2];
    const float* W1   = (const float*)d_in[3];
    const float* b1   = (const float*)d_in[4];
    const float* W2   = (const float*)d_in[5];
    const float* b2   = (const float*)d_in[6];
    const float* W3   = (const float*)d_in[7];
    const float* b3   = (const float*)d_in[8];
    const float* W4   = (const float*)d_in[9];
    const float* b4   = (const float*)d_in[10];
    float* out = (float*)d_out;

    // workspace layout (all 256B-aligned)
    char* p = (char*)d_ws;
    float* mean   = (float*)p;                    p += (size_t)NN * H2 * 4;     // 51.2 MB
    int*   perm   = (int*)p;                      p += (size_t)NE * 4;          // 6.4 MB
    int*   row_ptr= (int*)p;                      p += ((size_t)NN + 8) * 4;
    int*   cursor = (int*)p;                      p += (size_t)NN * 4;
    int*   cnt    = (int*)p;                      p += (size_t)NN * 4;

    hipMemsetAsync(cnt, 0, (size_t)NN * 4, stream);

    hist_kernel <<<(NE + 255) / 256, 256,  0, stream>>>(eidx, cnt);
    scan_kernel <<<1, 1024, 0, stream>>>(cnt, row_ptr, cursor);
    build_kernel<<<(NE + 255) / 256, 256,  0, stream>>>(eidx, cursor, perm);
    edge_agg_kernel<<<NN / NBN, 256, 0, stream>>>(x, eidx, ea, W1, b1, W2, b2,
                                                  row_ptr, perm, mean);
    node_kernel<<<NN / NB, 256, 0, stream>>>(x, W3, b3, W4, b4, mean, out);
}

// Round 4
// 1911.274 us; speedup vs baseline: 6.2168x; 1.3464x over previous
//
#include <hip/hip_runtime.h>
#include <hip/hip_bf16.h>

#define NN 100000
#define NE 1600000
#define XD 4
#define ED 39
#define K1 43    // XD+ED
#define H1 64
#define H2 128
#define H3 256
#define NBN 16   // nodes per block in edge_agg kernel
#define NBK 16   // nodes per block in node kernel

#define SIN_STR 45   // sIn row stride (odd -> conflict-free b32 cols)
#define SH1_STR 68   // sH1T row stride (mult of 4 -> aligned b128, 2-way max)
#define SRED_STR 69  // reduction buf stride (odd -> conflict-free)

// ---------------- pass 1: indegree histogram
__global__ __launch_bounds__(256) void hist_kernel(const int* __restrict__ eidx,
                                                   int* __restrict__ cnt) {
    int e = blockIdx.x * 256 + threadIdx.x;
    if (e < NE) atomicAdd(&cnt[eidx[e]], 1);
}

// ---------------- pass 2: single-block scan -> row_ptr (incl-shifted) + cursor (excl)
__global__ __launch_bounds__(1024) void scan_kernel(const int* __restrict__ cnt,
                                                    int* __restrict__ row_ptr,
                                                    int* __restrict__ cursor) {
    __shared__ int wsum[16];
    const int t = threadIdx.x, lane = t & 63, w = t >> 6;
    int carry = 0;
    if (t == 0) row_ptr[0] = 0;
    for (int base = 0; base < NN; base += 1024) {
        int i = base + t;
        int v = (i < NN) ? cnt[i] : 0;
        int s = v;
        #pragma unroll
        for (int d = 1; d < 64; d <<= 1) {
            int u = __shfl_up(s, d, 64);
            if (lane >= d) s += u;
        }
        if (lane == 63) wsum[w] = s;
        __syncthreads();
        if (w == 0 && lane < 16) {
            int e = wsum[lane];
            #pragma unroll
            for (int d = 1; d < 16; d <<= 1) {
                int u = __shfl_up(e, d, 64);
                if (lane >= d) e += u;
            }
            wsum[lane] = e;
        }
        __syncthreads();
        int woff = (w == 0) ? 0 : wsum[w - 1];
        int tot  = wsum[15];
        if (i < NN) {
            int incl = carry + woff + s;
            row_ptr[i + 1] = incl;
            cursor[i]      = incl - v;
        }
        carry += tot;
        __syncthreads();
    }
}

// ---------------- pass 3: scatter edge ids into dst-sorted order
__global__ __launch_bounds__(256) void build_kernel(const int* __restrict__ eidx,
                                                    int* __restrict__ cursor,
                                                    int* __restrict__ perm) {
    int e = blockIdx.x * 256 + threadIdx.x;
    if (e < NE) {
        int r = eidx[e];
        int pos = atomicAdd(&cursor[r], 1);
        perm[pos] = e;
    }
}

// ---------------- pass 4: edge MLP (register-tiled) + deterministic aggregation
__global__ __launch_bounds__(256, 4) void edge_agg_kernel(
    const float* __restrict__ x, const int* __restrict__ eidx,
    const float* __restrict__ ea,
    const float* __restrict__ W1, const float* __restrict__ b1,
    const float* __restrict__ W2, const float* __restrict__ b2,
    const int* __restrict__ row_ptr, const int* __restrict__ perm,
    float* __restrict__ mean)
{
    // union region: sIn [64][SIN_STR] | sH1T [64][SH1_STR]; reduction overlays it
    __shared__ __align__(16) float uReg[64 * SIN_STR + 64 * SH1_STR];
    __shared__ float accs[NBN][H2];
    __shared__ int sPerm[64], sCol[64], sRP[NBN + 1];

    const int t    = threadIdx.x;
    const int lane = t & 63;
    const int g    = t >> 6;
    const int n0   = blockIdx.x * NBN;

    if (t <= NBN) sRP[t] = row_ptr[n0 + t];
    for (int i = t; i < NBN * H2; i += 256) ((float*)accs)[i] = 0.f;
    __syncthreads();

    const int base = sRP[0], cntE = sRP[NBN] - base;

    float* sIn  = uReg;                  // [e 64][SIN_STR]
    float* sH1  = uReg + 64 * SIN_STR;   // [k 64][SH1_STR] (h1 transposed)
    float* sRed = uReg;                  // [c 64][SRED_STR]

    const int em = lane & 15;            // edge group
    const int e0 = em * 4;
    const int cs = lane >> 4;            // col sub-group 0..3
    const int c1 = g * 16 + cs * 4;      // L1 col base (4 cols)
    const int c2 = g * 32 + cs * 8;      // L2 col base (8 cols)

    float bb1[4], bb2[8];
    #pragma unroll
    for (int j = 0; j < 4; j++) bb1[j] = b1[c1 + j];
    #pragma unroll
    for (int j = 0; j < 8; j++) bb2[j] = b2[c2 + j];

    for (int tb = 0; tb < cntE; tb += 64) {
        const int nv = min(64, cntE - tb);
        if (t < 64) {
            int e = (t < nv) ? perm[base + tb + t] : -1;
            sPerm[t] = e;
            sCol[t]  = (e >= 0) ? eidx[NE + e] : 0;   // second row = col (source)
        }
        __syncthreads();

        // ---- stage inputs: x gather (4 floats/edge) + edge_attr rows
        {
            int e = t >> 2, k = t & 3;
            int ee = sPerm[e];
            sIn[e * SIN_STR + k] = (ee >= 0) ? x[sCol[e] * XD + k] : 0.f;
        }
        for (int i = t; i < 64 * ED; i += 256) {
            int e = i / ED, k = i - e * ED;
            int ee = sPerm[e];
            sIn[e * SIN_STR + XD + k] = (ee >= 0) ? ea[(size_t)ee * ED + k] : 0.f;
        }
        __syncthreads();

        // ---- layer 1: 4 edges x 4 cols per thread, weights streamed from global
        float a1[4][4];
        #pragma unroll
        for (int jc = 0; jc < 4; jc++)
            #pragma unroll
            for (int je = 0; je < 4; je++) a1[jc][je] = bb1[jc];

        #pragma unroll 4
        for (int k = 0; k < K1; k++) {
            float av[4];
            #pragma unroll
            for (int je = 0; je < 4; je++) av[je] = sIn[(e0 + je) * SIN_STR + k];
            float4 wv = *(const float4*)&W1[k * H1 + c1];
            float wj[4] = {wv.x, wv.y, wv.z, wv.w};
            #pragma unroll
            for (int jc = 0; jc < 4; jc++)
                #pragma unroll
                for (int je = 0; je < 4; je++)
                    a1[jc][je] = fmaf(av[je], wj[jc], a1[jc][je]);
        }
        // write h1 transposed [k=col][e], relu
        #pragma unroll
        for (int jc = 0; jc < 4; jc++) {
            float4 o;
            o.x = fmaxf(a1[jc][0], 0.f);
            o.y = fmaxf(a1[jc][1], 0.f);
            o.z = fmaxf(a1[jc][2], 0.f);
            o.w = fmaxf(a1[jc][3], 0.f);
            *(float4*)&sH1[(c1 + jc) * SH1_STR + e0] = o;
        }
        __syncthreads();

        // ---- layer 2: 4 edges x 8 cols per thread
        float a2[8][4];
        #pragma unroll
        for (int jc = 0; jc < 8; jc++)
            #pragma unroll
            for (int je = 0; je < 4; je++) a2[jc][je] = bb2[jc];

        #pragma unroll 4
        for (int k = 0; k < H1; k++) {
            float4 av4 = *(const float4*)&sH1[k * SH1_STR + e0];
            float av[4] = {av4.x, av4.y, av4.z, av4.w};
            float4 w0 = *(const float4*)&W2[k * H2 + c2];
            float4 w1 = *(const float4*)&W2[k * H2 + c2 + 4];
            float wj[8] = {w0.x, w0.y, w0.z, w0.w, w1.x, w1.y, w1.z, w1.w};
            #pragma unroll
            for (int jc = 0; jc < 8; jc++)
                #pragma unroll
                for (int je = 0; je < 4; je++)
                    a2[jc][je] = fmaf(av[je], wj[jc], a2[jc][je]);
        }
        __syncthreads();   // sIn/sH1 dead -> sRed may overlay

        // ---- segment-reduce h2 per node, two 64-col halves
        #pragma unroll
        for (int h = 0; h < 2; h++) {
            if ((g >> 1) == h) {
                const int cb = (g & 1) * 32 + cs * 8;   // col within half
                #pragma unroll
                for (int jc = 0; jc < 8; jc++)
                    #pragma unroll
                    for (int je = 0; je < 4; je++)
                        sRed[(cb + jc) * SRED_STR + e0 + je] = fmaxf(a2[jc][je], 0.f);
            }
            __syncthreads();
            {
                const int c = t & 63, q = t >> 6;
                for (int n = q * 4; n < q * 4 + 4; n++) {
                    int lo = sRP[n] - base - tb;     lo = lo < 0 ? 0 : lo;
                    int hi = sRP[n + 1] - base - tb; hi = hi > nv ? nv : hi;
                    float sum = 0.f;
                    for (int j = lo; j < hi; j++) sum += sRed[c * SRED_STR + j];
                    accs[n][h * 64 + c] += sum;
                }
            }
            __syncthreads();
        }
    }

    // write mean (exclusive ownership, non-atomic)
    for (int i = t; i < NBN * H2; i += 256) {
        int n = i >> 7, c = i & 127;
        int deg = sRP[n + 1] - sRP[n];
        float inv = (deg > 0) ? 1.f / (float)deg : 0.f;
        mean[(size_t)(n0 + n) * H2 + c] = accs[n][c] * inv;
    }
}

// ---------------- pass 5: node MLP, 4 nodes x 4 cols per thread
__global__ __launch_bounds__(256, 4) void node_kernel(
    const float* __restrict__ x,
    const float* __restrict__ W3, const float* __restrict__ b3,
    const float* __restrict__ W4, const float* __restrict__ b4,
    const float* __restrict__ mean,
    float* __restrict__ out)
{
    __shared__ float sIn[NBK * 133];
    __shared__ float sO1[NBK * 257];

    const int t  = threadIdx.x;
    const int n0 = blockIdx.x * NBK;
    const int s  = t & 63;          // col lane; cols s, s+64, s+128, s+192
    const int nw = (t >> 6) * 4;    // node base (wave-uniform)

    for (int i = t; i < NBK * 132; i += 256) {
        int n = i / 132, k = i - n * 132;
        sIn[n * 133 + k] = (k < XD) ? x[(n0 + n) * XD + k]
                                    : mean[(size_t)(n0 + n) * H2 + (k - XD)];
    }
    __syncthreads();

    // layer 3
    float acc[4][4];   // [node][col-instance]
    {
        float bb[4];
        #pragma unroll
        for (int ci = 0; ci < 4; ci++) bb[ci] = b3[s + 64 * ci];
        #pragma unroll
        for (int jn = 0; jn < 4; jn++)
            #pragma unroll
            for (int ci = 0; ci < 4; ci++) acc[jn][ci] = bb[ci];
    }
    #pragma unroll 4
    for (int k = 0; k < 132; k++) {
        float av[4];
        #pragma unroll
        for (int jn = 0; jn < 4; jn++) av[jn] = sIn[(nw + jn) * 133 + k];  // broadcast
        #pragma unroll
        for (int ci = 0; ci < 4; ci++) {
            float w = W3[k * H3 + s + 64 * ci];   // coalesced
            #pragma unroll
            for (int jn = 0; jn < 4; jn++)
                acc[jn][ci] = fmaf(av[jn], w, acc[jn][ci]);
        }
    }
    #pragma unroll
    for (int jn = 0; jn < 4; jn++)
        #pragma unroll
        for (int ci = 0; ci < 4; ci++)
            sO1[(nw + jn) * 257 + s + 64 * ci] = fmaxf(acc[jn][ci], 0.f);
    __syncthreads();

    // layer 4
    {
        float bb[4];
        #pragma unroll
        for (int ci = 0; ci < 4; ci++) bb[ci] = b4[s + 64 * ci];
        #pragma unroll
        for (int jn = 0; jn < 4; jn++)
            #pragma unroll
            for (int ci = 0; ci < 4; ci++) acc[jn][ci] = bb[ci];
    }
    #pragma unroll 4
    for (int k = 0; k < H3; k++) {
        float av[4];
        #pragma unroll
        for (int jn = 0; jn < 4; jn++) av[jn] = sO1[(nw + jn) * 257 + k];  // broadcast
        #pragma unroll
        for (int ci = 0; ci < 4; ci++) {
            float w = W4[k * H3 + s + 64 * ci];   // coalesced
            #pragma unroll
            for (int jn = 0; jn < 4; jn++)
                acc[jn][ci] = fmaf(av[jn], w, acc[jn][ci]);
        }
    }
    #pragma unroll
    for (int jn = 0; jn < 4; jn++)
        #pragma unroll
        for (int ci = 0; ci < 4; ci++)
            out[(size_t)(n0 + nw + jn) * H3 + s + 64 * ci] = fmaxf(acc[jn][ci], 0.f);
}

extern "C" void kernel_launch(void* const* d_in, const int* in_sizes, int n_in,
                              void* d_out, int out_size, void* d_ws, size_t ws_size,
                              hipStream_t stream) {
    const float* x    = (const float*)d_in[0];
    const int*   eidx = (const int*)  d_in[1];
    const float* ea   = (const float*)d_in[2];
    const float* W1   = (const float*)d_in[3];
    const float* b1   = (const float*)d_in[4];
    const float* W2   = (const float*)d_in[5];
    const float* b2   = (const float*)d_in[6];
    const float* W3   = (const float*)d_in[7];
    const float* b3   = (const float*)d_in[8];
    const float* W4   = (const float*)d_in[9];
    const float* b4   = (const float*)d_in[10];
    float* out = (float*)d_out;

    char* p = (char*)d_ws;
    float* mean    = (float*)p;  p += (size_t)NN * H2 * 4;
    int*   perm    = (int*)p;    p += (size_t)NE * 4;
    int*   row_ptr = (int*)p;    p += ((size_t)NN + 8) * 4;
    int*   cursor  = (int*)p;    p += (size_t)NN * 4;
    int*   cnt     = (int*)p;    p += (size_t)NN * 4;

    hipMemsetAsync(cnt, 0, (size_t)NN * 4, stream);

    hist_kernel <<<(NE + 255) / 256, 256, 0, stream>>>(eidx, cnt);
    scan_kernel <<<1, 1024, 0, stream>>>(cnt, row_ptr, cursor);
    build_kernel<<<(NE + 255) / 256, 256, 0, stream>>>(eidx, cursor, perm);
    edge_agg_kernel<<<NN / NBN, 256, 0, stream>>>(x, eidx, ea, W1, b1, W2, b2,
                                                  row_ptr, perm, mean);
    node_kernel<<<NN / NBK, 256, 0, stream>>>(x, W3, b3, W4, b4, mean, out);
}